// Round 6
// baseline (307.745 us; speedup 1.0000x reference)
//
#include <hip/hip_runtime.h>

typedef __attribute__((ext_vector_type(8))) short bf16x8;
typedef __attribute__((ext_vector_type(4))) short bf16x4;
typedef __attribute__((ext_vector_type(4))) float f32x4;

#define MFMA(a, b, c) __builtin_amdgcn_mfma_f32_16x16x32_bf16((a), (b), (c), 0, 0, 0)

__device__ __forceinline__ unsigned short f2bf(float f) {
  unsigned int x = __float_as_uint(f);
  return (unsigned short)((x + 0x7fffu + ((x >> 16) & 1u)) >> 16);
}
__device__ __forceinline__ unsigned int cvtpk(float lo, float hi) {
  unsigned int r;
  asm("v_cvt_pk_bf16_f32 %0, %1, %2" : "=v"(r) : "v"(lo), "v"(hi));
  return r;
}

constexpr int SEQ = 2048;
constexpr int NH = 8;
constexpr int DH = 128;
constexpr int DIM = 1024;
constexpr float SCALE = 0.08838834764831845f; // 1/sqrt(128)

// ---------------------------------------------------------------------------
// K1: qkv = x @ qkv_proj^T  (M=4096, N=3072, K=1024), fused RoPE epilogue.
// (round-4 form: f32 loads + cvt_pk staging)
// ---------------------------------------------------------------------------
__global__ __launch_bounds__(256) void k_qkv_rope(
    const float* __restrict__ x, const float* __restrict__ wqkv,
    const float* __restrict__ cosT, const float* __restrict__ sinT,
    unsigned short* __restrict__ q, unsigned short* __restrict__ k,
    unsigned short* __restrict__ vT)
{
  __shared__ __align__(16) unsigned short As[128][40];
  __shared__ __align__(16) unsigned short Bs[128][40];
  const int tid = threadIdx.x;
  const int wave = tid >> 6, lane = tid & 63;
  const int fr = lane & 15, fq = lane >> 4;
  const int fk = fq * 8;
  const int wr = (wave >> 1) * 64, wc = (wave & 1) * 64;
  const int m0 = blockIdx.x * 128, n0 = blockIdx.y * 128;

  f32x4 zero4 = {0.f, 0.f, 0.f, 0.f};
  f32x4 acc[4][4];
  for (int i = 0; i < 4; ++i)
    for (int j = 0; j < 4; ++j) acc[i][j] = zero4;

  for (int kt = 0; kt < 32; ++kt) {
    const int k0 = kt * 32;
    __syncthreads();
#pragma unroll
    for (int j = 0; j < 4; ++j) {
      int f = j * 256 + tid;
      int row = f >> 3, c4 = (f & 7) * 4;
      f32x4 va = *(const f32x4*)(x + (m0 + row) * 1024 + k0 + c4);
      f32x4 vb = *(const f32x4*)(wqkv + (n0 + row) * 1024 + k0 + c4);
      uint2 ua, ub;
      ua.x = cvtpk(va[0], va[1]); ua.y = cvtpk(va[2], va[3]);
      ub.x = cvtpk(vb[0], vb[1]); ub.y = cvtpk(vb[2], vb[3]);
      *(uint2*)&As[row][c4] = ua;
      *(uint2*)&Bs[row][c4] = ub;
    }
    __syncthreads();
    bf16x8 af[4], bfr[4];
#pragma unroll
    for (int mi = 0; mi < 4; ++mi) af[mi] = *(const bf16x8*)&As[wr + mi * 16 + fr][fk];
#pragma unroll
    for (int ni = 0; ni < 4; ++ni) bfr[ni] = *(const bf16x8*)&Bs[wc + ni * 16 + fr][fk];
#pragma unroll
    for (int mi = 0; mi < 4; ++mi)
#pragma unroll
      for (int ni = 0; ni < 4; ++ni)
        acc[mi][ni] = MFMA(af[mi], bfr[ni], acc[mi][ni]);
  }

#pragma unroll
  for (int mi = 0; mi < 4; ++mi)
#pragma unroll
    for (int ni = 0; ni < 4; ++ni)
#pragma unroll
      for (int r = 0; r < 4; ++r) {
        float val = acc[mi][ni][r];
        float other = __shfl_xor(val, 1, 64);
        int m = m0 + wr + mi * 16 + fq * 4 + r;
        int n = n0 + wc + ni * 16 + fr;
        int a = n >> 10, feat = n & 1023;
        int hh = feat >> 7, dh = feat & 127;
        int bi = m >> 11, t = m & 2047;
        if (a == 2) {
          vT[((bi * NH + hh) * DH + dh) * SEQ + t] = f2bf(val);
        } else {
          float c = cosT[t * 64 + (dh >> 1)];
          float s = sinT[t * 64 + (dh >> 1)];
          float o = ((dh & 1) == 0) ? (val * c - other * s) : (other * s + val * c);
          unsigned short* dst = (a == 0) ? q : k;
          dst[((bi * NH + hh) * SEQ + t) * DH + dh] = f2bf(o);
        }
      }
}

// ---------------------------------------------------------------------------
// K2: causal attention, barrier-free. Each wave owns 16 rows; K/V read
// directly from global (L2-resident: 512KB/head). Only per-wave Esc
// transpose in LDS. Pass A: rowsums. Pass B: attn write + PV.
// ---------------------------------------------------------------------------
__global__ __launch_bounds__(256) void k_attn(
    const unsigned short* __restrict__ q, const unsigned short* __restrict__ k,
    const unsigned short* __restrict__ vT,
    float* __restrict__ attn, unsigned short* __restrict__ heads)
{
  __shared__ __align__(16) unsigned short Esc[4][16][40]; // 5 KB total

  const int tid = threadIdx.x;
  const int wave = tid >> 6, lane = tid & 63;
  const int fr = lane & 15, fq = lane >> 4;
  const int fk = fq * 8;
  const int rt = (blockIdx.z == 0) ? (int)blockIdx.x : (31 - (int)blockIdx.x);
  const int row0 = rt * 64;
  const int hh = blockIdx.y, bi = blockIdx.z;
  const int bh = bi * NH + hh;
  const int r0 = row0 + wave * 16;

  const unsigned short* qb = q + bh * SEQ * DH;
  const unsigned short* kb = k + bh * SEQ * DH;
  const unsigned short* vb = vT + bh * DH * SEQ;

  bf16x8 aq[4];
#pragma unroll
  for (int ks = 0; ks < 4; ++ks)
    aq[ks] = *(const bf16x8*)(qb + (r0 + fr) * DH + ks * 32 + fk);

  const int wmax = r0 + 15;
  const int nc = r0 >> 5; // last 32-col chunk index for this wave

  float rs[4] = {0.f, 0.f, 0.f, 0.f};

  // ---- pass A: row sums of exp over causal prefix ----
  for (int cc = 0; cc <= nc; ++cc) {
    const int c0 = cc * 32;
#pragma unroll
    for (int half = 0; half < 2; ++half) {
      const int ch = c0 + half * 16;
      if (ch <= wmax) {
        bf16x8 bk[4];
#pragma unroll
        for (int ks = 0; ks < 4; ++ks)
          bk[ks] = *(const bf16x8*)(kb + (ch + fr) * DH + ks * 32 + fk);
        f32x4 s = {0.f, 0.f, 0.f, 0.f};
        __builtin_amdgcn_s_setprio(1);
#pragma unroll
        for (int ks = 0; ks < 4; ++ks) s = MFMA(aq[ks], bk[ks], s);
        __builtin_amdgcn_s_setprio(0);
        const int col = ch + fr;
#pragma unroll
        for (int r = 0; r < 4; ++r) {
          int row = r0 + fq * 4 + r;
          if (col <= row) rs[r] += __expf(s[r] * SCALE);
        }
      }
    }
  }

#pragma unroll
  for (int r = 0; r < 4; ++r)
#pragma unroll
    for (int msk = 1; msk < 16; msk <<= 1)
      rs[r] += __shfl_xor(rs[r], msk, 64);

  float inv[4];
#pragma unroll
  for (int r = 0; r < 4; ++r) inv[r] = 1.0f / rs[r];

  f32x4 pv[8];
  {
    f32x4 zero4 = {0.f, 0.f, 0.f, 0.f};
#pragma unroll
    for (int i = 0; i < 8; ++i) pv[i] = zero4;
  }

  // ---- pass B: normalized f32 attn + PV (32-col chunks) ----
  for (int cc = 0; cc <= nc; ++cc) {
    const int c0 = cc * 32;
    // prefetch V fragments for this chunk (latency hides under QK+exp)
    bf16x8 bv[8];
#pragma unroll
    for (int ni = 0; ni < 8; ++ni)
      bv[ni] = *(const bf16x8*)(vb + (ni * 16 + fr) * SEQ + c0 + fk);

#pragma unroll
    for (int half = 0; half < 2; ++half) {
      const int ch = c0 + half * 16;
      const bool live = (ch <= wmax);
      f32x4 s = {0.f, 0.f, 0.f, 0.f};
      if (live) {
        bf16x8 bk[4];
#pragma unroll
        for (int ks = 0; ks < 4; ++ks)
          bk[ks] = *(const bf16x8*)(kb + (ch + fr) * DH + ks * 32 + fk);
        __builtin_amdgcn_s_setprio(1);
#pragma unroll
        for (int ks = 0; ks < 4; ++ks) s = MFMA(aq[ks], bk[ks], s);
        __builtin_amdgcn_s_setprio(0);
      }
      const int col = ch + fr;
#pragma unroll
      for (int r = 0; r < 4; ++r) {
        int row = r0 + fq * 4 + r;
        float p = (live && col <= row) ? __expf(s[r] * SCALE) * inv[r] : 0.f;
        attn[((size_t)bh * SEQ + row) * SEQ + col] = p;
        Esc[wave][fq * 4 + r][half * 16 + fr] = f2bf(p);
      }
    }
    // per-wave transpose readback (same-wave LDS; DS ops in order)
    bf16x8 ae = *(const bf16x8*)&Esc[wave][fr][fk];
    __builtin_amdgcn_s_setprio(1);
#pragma unroll
    for (int ni = 0; ni < 8; ++ni) pv[ni] = MFMA(ae, bv[ni], pv[ni]);
    __builtin_amdgcn_s_setprio(0);
  }

#pragma unroll
  for (int ni = 0; ni < 8; ++ni)
#pragma unroll
    for (int r = 0; r < 4; ++r) {
      int row = r0 + fq * 4 + r;
      int dh = ni * 16 + fr;
      heads[(bi * SEQ + row) * DIM + hh * DH + dh] = f2bf(pv[ni][r]);
    }

  // ---- tail: zero cols [(r0 & ~31)+32, 2048) for this wave's 16 rows ----
  {
    const int zstart = (r0 & ~31) + 32;
    f32x4 z4 = {0.f, 0.f, 0.f, 0.f};
#pragma unroll
    for (int rr = 0; rr < 4; ++rr) {
      int row = r0 + rr * 4 + fq;
      float* dst = attn + ((size_t)bh * SEQ + row) * SEQ;
      for (int c = zstart + fr * 4; c < SEQ; c += 64)
        *(f32x4*)(dst + c) = z4;
    }
  }
}

// ---------------------------------------------------------------------------
// K3: out = heads @ w_out^T  (M=4096, N=1024, K=1024), f32 output
// (round-4 form)
// ---------------------------------------------------------------------------
__global__ __launch_bounds__(256) void k_outproj(
    const unsigned short* __restrict__ heads, const float* __restrict__ wout,
    float* __restrict__ out)
{
  __shared__ __align__(16) unsigned short As[128][40];
  __shared__ __align__(16) unsigned short Bs[128][40];
  const int tid = threadIdx.x;
  const int wave = tid >> 6, lane = tid & 63;
  const int fr = lane & 15, fq = lane >> 4;
  const int fk = fq * 8;
  const int wr = (wave >> 1) * 64, wc = (wave & 1) * 64;
  const int m0 = blockIdx.x * 128, n0 = blockIdx.y * 128;

  f32x4 zero4 = {0.f, 0.f, 0.f, 0.f};
  f32x4 acc[4][4];
  for (int i = 0; i < 4; ++i)
    for (int j = 0; j < 4; ++j) acc[i][j] = zero4;

  for (int kt = 0; kt < 32; ++kt) {
    const int k0 = kt * 32;
    __syncthreads();
#pragma unroll
    for (int j = 0; j < 2; ++j) { // A tile: 128x32 bf16
      int f = j * 256 + tid;
      int row = f >> 2, c = (f & 3) * 8;
      *(bf16x8*)&As[row][c] = *(const bf16x8*)(heads + (m0 + row) * 1024 + k0 + c);
    }
#pragma unroll
    for (int j = 0; j < 4; ++j) { // B tile: 128x32 f32 -> bf16 via cvt_pk
      int f = j * 256 + tid;
      int row = f >> 3, c4 = (f & 7) * 4;
      f32x4 vb = *(const f32x4*)(wout + (n0 + row) * 1024 + k0 + c4);
      uint2 ub;
      ub.x = cvtpk(vb[0], vb[1]); ub.y = cvtpk(vb[2], vb[3]);
      *(uint2*)&Bs[row][c4] = ub;
    }
    __syncthreads();
    bf16x8 af[4], bfr[4];
#pragma unroll
    for (int mi = 0; mi < 4; ++mi) af[mi] = *(const bf16x8*)&As[wr + mi * 16 + fr][fk];
#pragma unroll
    for (int ni = 0; ni < 4; ++ni) bfr[ni] = *(const bf16x8*)&Bs[wc + ni * 16 + fr][fk];
#pragma unroll
    for (int mi = 0; mi < 4; ++mi)
#pragma unroll
      for (int ni = 0; ni < 4; ++ni)
        acc[mi][ni] = MFMA(af[mi], bfr[ni], acc[mi][ni]);
  }

#pragma unroll
  for (int mi = 0; mi < 4; ++mi)
#pragma unroll
    for (int ni = 0; ni < 4; ++ni)
#pragma unroll
      for (int r = 0; r < 4; ++r) {
        int m = m0 + wr + mi * 16 + fq * 4 + r;
        int n = n0 + wc + ni * 16 + fr;
        out[m * 1024 + n] = acc[mi][ni][r];
      }
}

extern "C" void kernel_launch(void* const* d_in, const int* in_sizes, int n_in,
                              void* d_out, int out_size, void* d_ws, size_t ws_size,
                              hipStream_t stream)
{
  const float* x    = (const float*)d_in[0];
  const float* wqkv = (const float*)d_in[1];
  const float* wout = (const float*)d_in[2];
  const float* cosT = (const float*)d_in[3];
  const float* sinT = (const float*)d_in[4];

  float* out  = (float*)d_out;
  float* attn = out + 4194304;
  unsigned short* ws = (unsigned short*)d_ws;
  unsigned short* q     = ws;             // (B,H,T,DH) bf16
  unsigned short* kk    = ws + 4194304;   // (B,H,T,DH) bf16
  unsigned short* vT    = ws + 8388608;   // (B,H,DH,T) bf16
  unsigned short* heads = ws + 12582912;  // (B,T,DIM) bf16

  k_qkv_rope<<<dim3(32, 24), 256, 0, stream>>>(x, wqkv, cosT, sinT, q, kk, vT);
  k_attn<<<dim3(32, 8, 2), 256, 0, stream>>>(q, kk, vT, attn, heads);
  k_outproj<<<dim3(32, 8), 256, 0, stream>>>(heads, wout, out);
}

// Round 7
// 245.502 us; speedup vs baseline: 1.2535x; 1.2535x over previous
//
#include <hip/hip_runtime.h>

typedef __attribute__((ext_vector_type(8))) short bf16x8;
typedef __attribute__((ext_vector_type(4))) short bf16x4;
typedef __attribute__((ext_vector_type(4))) float f32x4;

#define MFMA(a, b, c) __builtin_amdgcn_mfma_f32_16x16x32_bf16((a), (b), (c), 0, 0, 0)

__device__ __forceinline__ unsigned short f2bf(float f) {
  unsigned int x = __float_as_uint(f);
  return (unsigned short)((x + 0x7fffu + ((x >> 16) & 1u)) >> 16);
}
__device__ __forceinline__ unsigned int cvtpk(float lo, float hi) {
  unsigned int r;
  asm("v_cvt_pk_bf16_f32 %0, %1, %2" : "=v"(r) : "v"(lo), "v"(hi));
  return r;
}

constexpr int SEQ = 2048;
constexpr int NH = 8;
constexpr int DH = 128;
constexpr int DIM = 1024;
constexpr float SCALE = 0.08838834764831845f; // 1/sqrt(128)

// ---------------------------------------------------------------------------
// K1: qkv = x @ qkv_proj^T  (M=4096, N=3072, K=1024), fused RoPE epilogue.
// (round-4 form: f32 loads + cvt_pk staging; best measured)
// ---------------------------------------------------------------------------
__global__ __launch_bounds__(256) void k_qkv_rope(
    const float* __restrict__ x, const float* __restrict__ wqkv,
    const float* __restrict__ cosT, const float* __restrict__ sinT,
    unsigned short* __restrict__ q, unsigned short* __restrict__ k,
    unsigned short* __restrict__ vT)
{
  __shared__ __align__(16) unsigned short As[128][40];
  __shared__ __align__(16) unsigned short Bs[128][40];
  const int tid = threadIdx.x;
  const int wave = tid >> 6, lane = tid & 63;
  const int fr = lane & 15, fq = lane >> 4;
  const int fk = fq * 8;
  const int wr = (wave >> 1) * 64, wc = (wave & 1) * 64;
  const int m0 = blockIdx.x * 128, n0 = blockIdx.y * 128;

  f32x4 zero4 = {0.f, 0.f, 0.f, 0.f};
  f32x4 acc[4][4];
  for (int i = 0; i < 4; ++i)
    for (int j = 0; j < 4; ++j) acc[i][j] = zero4;

  for (int kt = 0; kt < 32; ++kt) {
    const int k0 = kt * 32;
    __syncthreads();
#pragma unroll
    for (int j = 0; j < 4; ++j) {
      int f = j * 256 + tid;
      int row = f >> 3, c4 = (f & 7) * 4;
      f32x4 va = *(const f32x4*)(x + (m0 + row) * 1024 + k0 + c4);
      f32x4 vb = *(const f32x4*)(wqkv + (n0 + row) * 1024 + k0 + c4);
      uint2 ua, ub;
      ua.x = cvtpk(va[0], va[1]); ua.y = cvtpk(va[2], va[3]);
      ub.x = cvtpk(vb[0], vb[1]); ub.y = cvtpk(vb[2], vb[3]);
      *(uint2*)&As[row][c4] = ua;
      *(uint2*)&Bs[row][c4] = ub;
    }
    __syncthreads();
    bf16x8 af[4], bfr[4];
#pragma unroll
    for (int mi = 0; mi < 4; ++mi) af[mi] = *(const bf16x8*)&As[wr + mi * 16 + fr][fk];
#pragma unroll
    for (int ni = 0; ni < 4; ++ni) bfr[ni] = *(const bf16x8*)&Bs[wc + ni * 16 + fr][fk];
#pragma unroll
    for (int mi = 0; mi < 4; ++mi)
#pragma unroll
      for (int ni = 0; ni < 4; ++ni)
        acc[mi][ni] = MFMA(af[mi], bfr[ni], acc[mi][ni]);
  }

#pragma unroll
  for (int mi = 0; mi < 4; ++mi)
#pragma unroll
    for (int ni = 0; ni < 4; ++ni)
#pragma unroll
      for (int r = 0; r < 4; ++r) {
        float val = acc[mi][ni][r];
        float other = __shfl_xor(val, 1, 64);
        int m = m0 + wr + mi * 16 + fq * 4 + r;
        int n = n0 + wc + ni * 16 + fr;
        int a = n >> 10, feat = n & 1023;
        int hh = feat >> 7, dh = feat & 127;
        int bi = m >> 11, t = m & 2047;
        if (a == 2) {
          vT[((bi * NH + hh) * DH + dh) * SEQ + t] = f2bf(val);
        } else {
          float c = cosT[t * 64 + (dh >> 1)];
          float s = sinT[t * 64 + (dh >> 1)];
          float o = ((dh & 1) == 0) ? (val * c - other * s) : (other * s + val * c);
          unsigned short* dst = (a == 0) ? q : k;
          dst[((bi * NH + hh) * SEQ + t) * DH + dh] = f2bf(o);
        }
      }
}

// ---------------------------------------------------------------------------
// K2: causal attention per (b, head, 64-row tile). Single-barrier pipelined:
// K reg->LDS double-buffered (issue next-tile loads BEFORE compute, ds_write
// after, one __syncthreads per tile). V streamed via register prefetch at
// tile start. Pass A: rowsums. Pass B (reverse tile order, reuses last-staged
// tile): f32 attn write + PV. Tail: zero cols [row0+64, 2048).
// ---------------------------------------------------------------------------
__global__ __launch_bounds__(256) void k_attn(
    const unsigned short* __restrict__ q, const unsigned short* __restrict__ k,
    const unsigned short* __restrict__ vT,
    float* __restrict__ attn, unsigned short* __restrict__ heads)
{
  __shared__ __align__(16) unsigned short Kt[2][64][140]; // ~35.8 KB, pitch 140: conflict-free
  __shared__ __align__(16) unsigned short Esc[4][16][40]; // 5 KB per-wave P transpose

  const int tid = threadIdx.x;
  const int wave = tid >> 6, lane = tid & 63;
  const int fr = lane & 15, fq = lane >> 4;
  const int fk = fq * 8;
  const int rt = (blockIdx.z == 0) ? (int)blockIdx.x : (31 - (int)blockIdx.x);
  const int row0 = rt * 64;
  const int hh = blockIdx.y, bi = blockIdx.z;
  const int bh = bi * NH + hh;
  const int r0 = row0 + wave * 16;

  const unsigned short* qb = q + bh * SEQ * DH;
  const unsigned short* kb = k + bh * SEQ * DH;
  const unsigned short* vb = vT + bh * DH * SEQ;

  bf16x8 aq[4];
#pragma unroll
  for (int ks = 0; ks < 4; ++ks)
    aq[ks] = *(const bf16x8*)(qb + (r0 + fr) * DH + ks * 32 + fk);

  const int ntiles = rt + 1;      // 64-col K tiles
  const int wmax = r0 + 15;
  const int trow = tid >> 4;      // staging: 16 rows/j-slab, 4 slabs
  const int tcol = (tid & 15) * 8;

  bf16x8 kreg[4];
  // ---- prologue: stage tile 0 into buf 0 ----
#pragma unroll
  for (int j = 0; j < 4; ++j)
    kreg[j] = *(const bf16x8*)(kb + (j * 16 + trow) * DH + tcol);
#pragma unroll
  for (int j = 0; j < 4; ++j)
    *(bf16x8*)&Kt[0][j * 16 + trow][tcol] = kreg[j];
  __syncthreads();

  int cur = 0;
  float rs[4] = {0.f, 0.f, 0.f, 0.f};

  // ---- pass A: row sums (forward tiles) ----
  for (int nt = 0; nt < ntiles; ++nt) {
    const int c0 = nt * 64;
    const bool pf = (nt + 1 < ntiles);
    if (pf) { // issue next-tile loads; latency hides under compute
#pragma unroll
      for (int j = 0; j < 4; ++j)
        kreg[j] = *(const bf16x8*)(kb + (c0 + 64 + j * 16 + trow) * DH + tcol);
    }
#pragma unroll
    for (int half = 0; half < 4; ++half) {
      const int ch = c0 + half * 16;
      if (ch <= wmax) {
        f32x4 s = {0.f, 0.f, 0.f, 0.f};
#pragma unroll
        for (int ks = 0; ks < 4; ++ks) {
          bf16x8 bk = *(const bf16x8*)&Kt[cur][half * 16 + fr][ks * 32 + fk];
          s = MFMA(aq[ks], bk, s);
        }
        const int col = ch + fr;
#pragma unroll
        for (int r = 0; r < 4; ++r)
          if (col <= r0 + fq * 4 + r) rs[r] += __expf(s[r] * SCALE);
      }
    }
    if (pf) {
#pragma unroll
      for (int j = 0; j < 4; ++j)
        *(bf16x8*)&Kt[cur ^ 1][j * 16 + trow][tcol] = kreg[j];
    }
    __syncthreads();
    if (pf) cur ^= 1;
  }

#pragma unroll
  for (int r = 0; r < 4; ++r)
#pragma unroll
    for (int msk = 1; msk < 16; msk <<= 1)
      rs[r] += __shfl_xor(rs[r], msk, 64);

  float inv[4];
#pragma unroll
  for (int r = 0; r < 4; ++r) inv[r] = 1.0f / rs[r];

  f32x4 pv[8];
  {
    f32x4 zero4 = {0.f, 0.f, 0.f, 0.f};
#pragma unroll
    for (int i = 0; i < 8; ++i) pv[i] = zero4;
  }

  // ---- pass B: reverse tiles (Kt[cur] already holds tile ntiles-1) ----
  for (int nt = ntiles - 1; nt >= 0; --nt) {
    const int c0 = nt * 64;
    const bool pf = (nt > 0);
    // V register prefetch for both 32-col chunks of this tile
    bf16x8 bv[16];
#pragma unroll
    for (int ni = 0; ni < 8; ++ni) {
      bv[ni]     = *(const bf16x8*)(vb + (ni * 16 + fr) * SEQ + c0 + fk);
      bv[8 + ni] = *(const bf16x8*)(vb + (ni * 16 + fr) * SEQ + c0 + 32 + fk);
    }
    if (pf) {
#pragma unroll
      for (int j = 0; j < 4; ++j)
        kreg[j] = *(const bf16x8*)(kb + (c0 - 64 + j * 16 + trow) * DH + tcol);
    }
#pragma unroll
    for (int chunk = 0; chunk < 2; ++chunk) {
#pragma unroll
      for (int h2 = 0; h2 < 2; ++h2) {
        const int half = chunk * 2 + h2;
        const int ch = c0 + half * 16;
        const bool live = (ch <= wmax);
        f32x4 s = {0.f, 0.f, 0.f, 0.f};
        if (live) {
#pragma unroll
          for (int ks = 0; ks < 4; ++ks) {
            bf16x8 bk = *(const bf16x8*)&Kt[cur][half * 16 + fr][ks * 32 + fk];
            s = MFMA(aq[ks], bk, s);
          }
        }
        const int col = ch + fr;
#pragma unroll
        for (int r = 0; r < 4; ++r) {
          int row = r0 + fq * 4 + r;
          float p = (live && col <= row) ? __expf(s[r] * SCALE) * inv[r] : 0.f;
          attn[((size_t)bh * SEQ + row) * SEQ + col] = p;
          Esc[wave][fq * 4 + r][h2 * 16 + fr] = f2bf(p);
        }
      }
      bf16x8 ae = *(const bf16x8*)&Esc[wave][fr][fk]; // same-wave DS ordering
#pragma unroll
      for (int ni = 0; ni < 8; ++ni)
        pv[ni] = MFMA(ae, bv[chunk * 8 + ni], pv[ni]);
    }
    if (pf) {
#pragma unroll
      for (int j = 0; j < 4; ++j)
        *(bf16x8*)&Kt[cur ^ 1][j * 16 + trow][tcol] = kreg[j];
    }
    __syncthreads();
    if (pf) cur ^= 1;
  }

#pragma unroll
  for (int ni = 0; ni < 8; ++ni)
#pragma unroll
    for (int r = 0; r < 4; ++r) {
      int row = r0 + fq * 4 + r;
      int dh = ni * 16 + fr;
      heads[(bi * SEQ + row) * DIM + hh * DH + dh] = f2bf(pv[ni][r]);
    }

  // ---- tail: zero cols [row0+64, 2048) for this wave's 16 rows ----
  {
    const int zstart = row0 + 64;
    f32x4 z4 = {0.f, 0.f, 0.f, 0.f};
#pragma unroll
    for (int rr = 0; rr < 4; ++rr) {
      int row = r0 + rr * 4 + fq;
      float* dst = attn + ((size_t)bh * SEQ + row) * SEQ;
      for (int c = zstart + fr * 4; c < SEQ; c += 64)
        *(f32x4*)(dst + c) = z4;
    }
  }
}

// ---------------------------------------------------------------------------
// K3: out = heads @ w_out^T  (M=4096, N=1024, K=1024), f32 output
// (round-4 form)
// ---------------------------------------------------------------------------
__global__ __launch_bounds__(256) void k_outproj(
    const unsigned short* __restrict__ heads, const float* __restrict__ wout,
    float* __restrict__ out)
{
  __shared__ __align__(16) unsigned short As[128][40];
  __shared__ __align__(16) unsigned short Bs[128][40];
  const int tid = threadIdx.x;
  const int wave = tid >> 6, lane = tid & 63;
  const int fr = lane & 15, fq = lane >> 4;
  const int fk = fq * 8;
  const int wr = (wave >> 1) * 64, wc = (wave & 1) * 64;
  const int m0 = blockIdx.x * 128, n0 = blockIdx.y * 128;

  f32x4 zero4 = {0.f, 0.f, 0.f, 0.f};
  f32x4 acc[4][4];
  for (int i = 0; i < 4; ++i)
    for (int j = 0; j < 4; ++j) acc[i][j] = zero4;

  for (int kt = 0; kt < 32; ++kt) {
    const int k0 = kt * 32;
    __syncthreads();
#pragma unroll
    for (int j = 0; j < 2; ++j) { // A tile: 128x32 bf16
      int f = j * 256 + tid;
      int row = f >> 2, c = (f & 3) * 8;
      *(bf16x8*)&As[row][c] = *(const bf16x8*)(heads + (m0 + row) * 1024 + k0 + c);
    }
#pragma unroll
    for (int j = 0; j < 4; ++j) { // B tile: 128x32 f32 -> bf16 via cvt_pk
      int f = j * 256 + tid;
      int row = f >> 3, c4 = (f & 7) * 4;
      f32x4 vb = *(const f32x4*)(wout + (n0 + row) * 1024 + k0 + c4);
      uint2 ub;
      ub.x = cvtpk(vb[0], vb[1]); ub.y = cvtpk(vb[2], vb[3]);
      *(uint2*)&Bs[row][c4] = ub;
    }
    __syncthreads();
    bf16x8 af[4], bfr[4];
#pragma unroll
    for (int mi = 0; mi < 4; ++mi) af[mi] = *(const bf16x8*)&As[wr + mi * 16 + fr][fk];
#pragma unroll
    for (int ni = 0; ni < 4; ++ni) bfr[ni] = *(const bf16x8*)&Bs[wc + ni * 16 + fr][fk];
#pragma unroll
    for (int mi = 0; mi < 4; ++mi)
#pragma unroll
      for (int ni = 0; ni < 4; ++ni)
        acc[mi][ni] = MFMA(af[mi], bfr[ni], acc[mi][ni]);
  }

#pragma unroll
  for (int mi = 0; mi < 4; ++mi)
#pragma unroll
    for (int ni = 0; ni < 4; ++ni)
#pragma unroll
      for (int r = 0; r < 4; ++r) {
        int m = m0 + wr + mi * 16 + fq * 4 + r;
        int n = n0 + wc + ni * 16 + fr;
        out[m * 1024 + n] = acc[mi][ni][r];
      }
}

extern "C" void kernel_launch(void* const* d_in, const int* in_sizes, int n_in,
                              void* d_out, int out_size, void* d_ws, size_t ws_size,
                              hipStream_t stream)
{
  const float* x    = (const float*)d_in[0];
  const float* wqkv = (const float*)d_in[1];
  const float* wout = (const float*)d_in[2];
  const float* cosT = (const float*)d_in[3];
  const float* sinT = (const float*)d_in[4];

  float* out  = (float*)d_out;
  float* attn = out + 4194304;
  unsigned short* ws = (unsigned short*)d_ws;
  unsigned short* q     = ws;             // (B,H,T,DH) bf16
  unsigned short* kk    = ws + 4194304;   // (B,H,T,DH) bf16
  unsigned short* vT    = ws + 8388608;   // (B,H,DH,T) bf16
  unsigned short* heads = ws + 12582912;  // (B,T,DIM) bf16

  k_qkv_rope<<<dim3(32, 24), 256, 0, stream>>>(x, wqkv, cosT, sinT, q, kk, vT);
  k_attn<<<dim3(32, 8, 2), 256, 0, stream>>>(q, kk, vT, attn, heads);
  k_outproj<<<dim3(32, 8), 256, 0, stream>>>(heads, wout, out);
}

// Round 8
// 236.578 us; speedup vs baseline: 1.3008x; 1.0377x over previous
//
#include <hip/hip_runtime.h>

typedef __attribute__((ext_vector_type(8))) short bf16x8;
typedef __attribute__((ext_vector_type(4))) short bf16x4;
typedef __attribute__((ext_vector_type(4))) float f32x4;

#define MFMA(a, b, c) __builtin_amdgcn_mfma_f32_16x16x32_bf16((a), (b), (c), 0, 0, 0)

__device__ __forceinline__ unsigned short f2bf(float f) {
  unsigned int x = __float_as_uint(f);
  return (unsigned short)((x + 0x7fffu + ((x >> 16) & 1u)) >> 16);
}
__device__ __forceinline__ unsigned int cvtpk(float lo, float hi) {
  unsigned int r;
  asm("v_cvt_pk_bf16_f32 %0, %1, %2" : "=v"(r) : "v"(lo), "v"(hi));
  return r;
}

constexpr int SEQ = 2048;
constexpr int NH = 8;
constexpr int DH = 128;
constexpr int DIM = 1024;
constexpr float SCALE = 0.08838834764831845f; // 1/sqrt(128)

// ---------------------------------------------------------------------------
// K1: qkv = x @ qkv_proj^T  (M=4096, N=3072, K=1024), fused RoPE epilogue.
// (round-4 form)
// ---------------------------------------------------------------------------
__global__ __launch_bounds__(256) void k_qkv_rope(
    const float* __restrict__ x, const float* __restrict__ wqkv,
    const float* __restrict__ cosT, const float* __restrict__ sinT,
    unsigned short* __restrict__ q, unsigned short* __restrict__ k,
    unsigned short* __restrict__ vT)
{
  __shared__ __align__(16) unsigned short As[128][40];
  __shared__ __align__(16) unsigned short Bs[128][40];
  const int tid = threadIdx.x;
  const int wave = tid >> 6, lane = tid & 63;
  const int fr = lane & 15, fq = lane >> 4;
  const int fk = fq * 8;
  const int wr = (wave >> 1) * 64, wc = (wave & 1) * 64;
  const int m0 = blockIdx.x * 128, n0 = blockIdx.y * 128;

  f32x4 zero4 = {0.f, 0.f, 0.f, 0.f};
  f32x4 acc[4][4];
  for (int i = 0; i < 4; ++i)
    for (int j = 0; j < 4; ++j) acc[i][j] = zero4;

  for (int kt = 0; kt < 32; ++kt) {
    const int k0 = kt * 32;
    __syncthreads();
#pragma unroll
    for (int j = 0; j < 4; ++j) {
      int f = j * 256 + tid;
      int row = f >> 3, c4 = (f & 7) * 4;
      f32x4 va = *(const f32x4*)(x + (m0 + row) * 1024 + k0 + c4);
      f32x4 vb = *(const f32x4*)(wqkv + (n0 + row) * 1024 + k0 + c4);
      uint2 ua, ub;
      ua.x = cvtpk(va[0], va[1]); ua.y = cvtpk(va[2], va[3]);
      ub.x = cvtpk(vb[0], vb[1]); ub.y = cvtpk(vb[2], vb[3]);
      *(uint2*)&As[row][c4] = ua;
      *(uint2*)&Bs[row][c4] = ub;
    }
    __syncthreads();
    bf16x8 af[4], bfr[4];
#pragma unroll
    for (int mi = 0; mi < 4; ++mi) af[mi] = *(const bf16x8*)&As[wr + mi * 16 + fr][fk];
#pragma unroll
    for (int ni = 0; ni < 4; ++ni) bfr[ni] = *(const bf16x8*)&Bs[wc + ni * 16 + fr][fk];
#pragma unroll
    for (int mi = 0; mi < 4; ++mi)
#pragma unroll
      for (int ni = 0; ni < 4; ++ni)
        acc[mi][ni] = MFMA(af[mi], bfr[ni], acc[mi][ni]);
  }

#pragma unroll
  for (int mi = 0; mi < 4; ++mi)
#pragma unroll
    for (int ni = 0; ni < 4; ++ni)
#pragma unroll
      for (int r = 0; r < 4; ++r) {
        float val = acc[mi][ni][r];
        float other = __shfl_xor(val, 1, 64);
        int m = m0 + wr + mi * 16 + fq * 4 + r;
        int n = n0 + wc + ni * 16 + fr;
        int a = n >> 10, feat = n & 1023;
        int hh = feat >> 7, dh = feat & 127;
        int bi = m >> 11, t = m & 2047;
        if (a == 2) {
          vT[((bi * NH + hh) * DH + dh) * SEQ + t] = f2bf(val);
        } else {
          float c = cosT[t * 64 + (dh >> 1)];
          float s = sinT[t * 64 + (dh >> 1)];
          float o = ((dh & 1) == 0) ? (val * c - other * s) : (other * s + val * c);
          unsigned short* dst = (a == 0) ? q : k;
          dst[((bi * NH + hh) * SEQ + t) * DH + dh] = f2bf(o);
        }
      }
}

// ---------------------------------------------------------------------------
// K2: causal attention (round-4 structure) with XCD-affinity block remap:
// 1-D grid of 512; xcd = n&7 pins bh in {xcd, xcd+8} so each XCD's L2 holds
// only its 2 heads' K/V (2 MB << 4 MB). Co-resident slots s, s+32 get
// rt = s and 31-s -> 33 tile-units per CU (balanced).
// ---------------------------------------------------------------------------
__global__ __launch_bounds__(256) void k_attn(
    const unsigned short* __restrict__ q, const unsigned short* __restrict__ k,
    const unsigned short* __restrict__ vT,
    float* __restrict__ attn, unsigned short* __restrict__ heads)
{
  __shared__ __align__(16) unsigned short Kt[64][140];
  __shared__ __align__(16) unsigned short Vt[128][76];
  __shared__ __align__(16) unsigned short Esc[4][16][76];

  const int tid = threadIdx.x;
  const int wave = tid >> 6, lane = tid & 63;
  const int fr = lane & 15, fq = lane >> 4;
  const int fk = fq * 8;

  // XCD-affinity decode
  const int n = blockIdx.x;
  const int xcd = n & 7;
  const int slot = n >> 3;          // [0,64)
  const int bh_hi = slot >> 5;      // 0/1
  const int rt0 = slot & 31;
  const int rt = bh_hi ? (31 - rt0) : rt0;
  const int bh = xcd + 8 * bh_hi;   // bi*8+hh
  const int bi = bh >> 3, hh = bh & 7;

  const int row0 = rt * 64;
  const int r0 = row0 + wave * 16;

  const unsigned short* qb = q + bh * SEQ * DH;
  const unsigned short* kb = k + bh * SEQ * DH;
  const unsigned short* vb = vT + bh * DH * SEQ;

  bf16x8 aq[4];
#pragma unroll
  for (int ks = 0; ks < 4; ++ks)
    aq[ks] = *(const bf16x8*)(qb + (r0 + fr) * DH + ks * 32 + fk);

  const int wmax = r0 + 15;
  float rs[4] = {0.f, 0.f, 0.f, 0.f};

  // ---- pass A: row sums (64-col tiles 0..rt) ----
  for (int nt = 0; nt <= rt; ++nt) {
    const int c0 = nt * 64;
    __syncthreads();
#pragma unroll
    for (int j = 0; j < 4; ++j) {
      int f = j * 256 + tid;
      int r = f >> 4, c = (f & 15) * 8;
      *(bf16x8*)&Kt[r][c] = *(const bf16x8*)(kb + (c0 + r) * DH + c);
    }
    __syncthreads();
#pragma unroll
    for (int half = 0; half < 4; ++half) {
      int ch = c0 + half * 16;
      if (ch <= wmax) {
        f32x4 s = {0.f, 0.f, 0.f, 0.f};
#pragma unroll
        for (int ks = 0; ks < 4; ++ks) {
          bf16x8 bk = *(const bf16x8*)&Kt[half * 16 + fr][ks * 32 + fk];
          s = MFMA(aq[ks], bk, s);
        }
        int col = ch + fr;
#pragma unroll
        for (int r = 0; r < 4; ++r) {
          int row = r0 + fq * 4 + r;
          if (col <= row) rs[r] += __expf(s[r] * SCALE);
        }
      }
    }
  }

#pragma unroll
  for (int r = 0; r < 4; ++r)
#pragma unroll
    for (int msk = 1; msk < 16; msk <<= 1)
      rs[r] += __shfl_xor(rs[r], msk, 64);

  float inv[4];
#pragma unroll
  for (int r = 0; r < 4; ++r) inv[r] = 1.0f / rs[r];

  f32x4 pv[8];
  {
    f32x4 zero4 = {0.f, 0.f, 0.f, 0.f};
#pragma unroll
    for (int i = 0; i < 8; ++i) pv[i] = zero4;
  }

  // ---- pass B: normalized attn write (f32) + PV ----
  for (int nt = 0; nt <= rt; ++nt) {
    const int c0 = nt * 64;
    __syncthreads();
#pragma unroll
    for (int j = 0; j < 4; ++j) {
      int f = j * 256 + tid;
      int r = f >> 4, c = (f & 15) * 8;
      *(bf16x8*)&Kt[r][c] = *(const bf16x8*)(kb + (c0 + r) * DH + c);
      int rv = f >> 3, cv = (f & 7) * 8;
      *(bf16x8*)&Vt[rv][cv] = *(const bf16x8*)(vb + rv * SEQ + c0 + cv);
    }
    __syncthreads();
#pragma unroll
    for (int half = 0; half < 4; ++half) {
      int ch = c0 + half * 16;
      bool live = (ch <= wmax);
      f32x4 s = {0.f, 0.f, 0.f, 0.f};
      if (live) {
#pragma unroll
        for (int ks = 0; ks < 4; ++ks) {
          bf16x8 bk = *(const bf16x8*)&Kt[half * 16 + fr][ks * 32 + fk];
          s = MFMA(aq[ks], bk, s);
        }
      }
      int col = ch + fr;
#pragma unroll
      for (int r = 0; r < 4; ++r) {
        int row = r0 + fq * 4 + r;
        float p = (live && col <= row) ? __expf(s[r] * SCALE) * inv[r] : 0.f;
        attn[((size_t)bh * SEQ + row) * SEQ + col] = p;
        Esc[wave][fq * 4 + r][half * 16 + fr] = f2bf(p);
      }
    }
    bf16x8 ae0 = *(const bf16x8*)&Esc[wave][fr][fk];
    bf16x8 ae1 = *(const bf16x8*)&Esc[wave][fr][32 + fk];
#pragma unroll
    for (int ni = 0; ni < 8; ++ni) {
      bf16x8 bv0 = *(const bf16x8*)&Vt[ni * 16 + fr][fk];
      bf16x8 bv1 = *(const bf16x8*)&Vt[ni * 16 + fr][32 + fk];
      pv[ni] = MFMA(ae0, bv0, pv[ni]);
      pv[ni] = MFMA(ae1, bv1, pv[ni]);
    }
  }

#pragma unroll
  for (int ni = 0; ni < 8; ++ni)
#pragma unroll
    for (int r = 0; r < 4; ++r) {
      int row = r0 + fq * 4 + r;
      int dh = ni * 16 + fr;
      heads[(bi * SEQ + row) * DIM + hh * DH + dh] = f2bf(pv[ni][r]);
    }

  // ---- tail: zero cols [row0+64, 2048) ----
  {
    const int zstart = row0 + 64;
    f32x4 z4 = {0.f, 0.f, 0.f, 0.f};
#pragma unroll
    for (int rr = 0; rr < 4; ++rr) {
      int row = r0 + rr * 4 + fq;
      float* dst = attn + ((size_t)bh * SEQ + row) * SEQ;
      for (int c = zstart + fr * 4; c < SEQ; c += 64)
        *(f32x4*)(dst + c) = z4;
    }
  }
}

// ---------------------------------------------------------------------------
// K3: out = heads @ w_out^T  (M=4096, N=1024, K=1024), f32 output
// (round-4 form)
// ---------------------------------------------------------------------------
__global__ __launch_bounds__(256) void k_outproj(
    const unsigned short* __restrict__ heads, const float* __restrict__ wout,
    float* __restrict__ out)
{
  __shared__ __align__(16) unsigned short As[128][40];
  __shared__ __align__(16) unsigned short Bs[128][40];
  const int tid = threadIdx.x;
  const int wave = tid >> 6, lane = tid & 63;
  const int fr = lane & 15, fq = lane >> 4;
  const int fk = fq * 8;
  const int wr = (wave >> 1) * 64, wc = (wave & 1) * 64;
  const int m0 = blockIdx.x * 128, n0 = blockIdx.y * 128;

  f32x4 zero4 = {0.f, 0.f, 0.f, 0.f};
  f32x4 acc[4][4];
  for (int i = 0; i < 4; ++i)
    for (int j = 0; j < 4; ++j) acc[i][j] = zero4;

  for (int kt = 0; kt < 32; ++kt) {
    const int k0 = kt * 32;
    __syncthreads();
#pragma unroll
    for (int j = 0; j < 2; ++j) { // A tile: 128x32 bf16
      int f = j * 256 + tid;
      int row = f >> 2, c = (f & 3) * 8;
      *(bf16x8*)&As[row][c] = *(const bf16x8*)(heads + (m0 + row) * 1024 + k0 + c);
    }
#pragma unroll
    for (int j = 0; j < 4; ++j) { // B tile: 128x32 f32 -> bf16 via cvt_pk
      int f = j * 256 + tid;
      int row = f >> 3, c4 = (f & 7) * 4;
      f32x4 vb = *(const f32x4*)(wout + (n0 + row) * 1024 + k0 + c4);
      uint2 ub;
      ub.x = cvtpk(vb[0], vb[1]); ub.y = cvtpk(vb[2], vb[3]);
      *(uint2*)&Bs[row][c4] = ub;
    }
    __syncthreads();
    bf16x8 af[4], bfr[4];
#pragma unroll
    for (int mi = 0; mi < 4; ++mi) af[mi] = *(const bf16x8*)&As[wr + mi * 16 + fr][fk];
#pragma unroll
    for (int ni = 0; ni < 4; ++ni) bfr[ni] = *(const bf16x8*)&Bs[wc + ni * 16 + fr][fk];
#pragma unroll
    for (int mi = 0; mi < 4; ++mi)
#pragma unroll
      for (int ni = 0; ni < 4; ++ni)
        acc[mi][ni] = MFMA(af[mi], bfr[ni], acc[mi][ni]);
  }

#pragma unroll
  for (int mi = 0; mi < 4; ++mi)
#pragma unroll
    for (int ni = 0; ni < 4; ++ni)
#pragma unroll
      for (int r = 0; r < 4; ++r) {
        int m = m0 + wr + mi * 16 + fq * 4 + r;
        int n = n0 + wc + ni * 16 + fr;
        out[m * 1024 + n] = acc[mi][ni][r];
      }
}

extern "C" void kernel_launch(void* const* d_in, const int* in_sizes, int n_in,
                              void* d_out, int out_size, void* d_ws, size_t ws_size,
                              hipStream_t stream)
{
  const float* x    = (const float*)d_in[0];
  const float* wqkv = (const float*)d_in[1];
  const float* wout = (const float*)d_in[2];
  const float* cosT = (const float*)d_in[3];
  const float* sinT = (const float*)d_in[4];

  float* out  = (float*)d_out;
  float* attn = out + 4194304;
  unsigned short* ws = (unsigned short*)d_ws;
  unsigned short* q     = ws;             // (B,H,T,DH) bf16
  unsigned short* kk    = ws + 4194304;   // (B,H,T,DH) bf16
  unsigned short* vT    = ws + 8388608;   // (B,H,DH,T) bf16
  unsigned short* heads = ws + 12582912;  // (B,T,DIM) bf16

  k_qkv_rope<<<dim3(32, 24), 256, 0, stream>>>(x, wqkv, cosT, sinT, q, kk, vT);
  k_attn<<<512, 256, 0, stream>>>(q, kk, vT, attn, heads);
  k_outproj<<<dim3(32, 8), 256, 0, stream>>>(heads, wout, out);
}